// Round 1
// baseline (4367.202 us; speedup 1.0000x reference)
//
#include <hip/hip_runtime.h>

// Problem constants: N=16, C_IN=32, C_OUT=64, H=W=128, D=5, K=800
#define R_SZ  (16*32*32*81)      // 1,327,104 floats
#define Q_SZ  (16*800*800)       // 10,240,000
#define P_SZ  (16*800*64)        // 819,200
#define LI_SZ (16*10*80*80)      // 1,024,000

__device__ __forceinline__ float alpha_scale(const float* alpha, const float* reg, int n) {
  // a = alpha[n] * (H*W*reg / (D*D*C_IN)) = alpha[n]*reg*16384/800
  return alpha[n] * (16384.0f * reg[0] / 800.0f);
}

// -------------------- init: R = 0, P = a * d^T --------------------
__global__ void k_init(float* __restrict__ R, float* __restrict__ P,
                       const float* __restrict__ d, const float* __restrict__ alpha,
                       const float* __restrict__ reg) {
  int idx = blockIdx.x * 256 + threadIdx.x;
  if (idx < R_SZ) R[idx] = 0.0f;
  int e = idx - R_SZ;
  if (e >= 0 && e < P_SZ) {
    int n = e / 51200; int q = e % 51200;
    int co = q / 800;  int k = q % 800;
    float a = alpha_scale(alpha, reg, n);
    P[(n*800 + k)*64 + co] = a * d[(n*64 + co)*800 + k];
  }
}

// -------------------- R[n,c1,c2,u,v] = sum_ij x[c1,i,j]*x[c2,i+u-4,j+v-4] ---
// grid = 16(n) * 9(u) * 8(row-chunk); block 256
__global__ __launch_bounds__(256) void k_corrR(const float* __restrict__ x,
                                               float* __restrict__ R) {
  int bid = blockIdx.x;
  int n = bid / 72;
  int rem = bid % 72;
  int u = rem / 8;
  int chunk = rem % 8;
  int du = u - 4;
  int i0 = chunk * 16;
  int lo = i0, hi = i0 + 16;
  if (du < 0 && lo < -du) lo = -du;
  if (du > 0 && hi > 128 - du) hi = 128 - du;

  __shared__ float as[128*34];   // as[j][c] = x[c][i][j], stride 34 (pad)
  __shared__ float bs[136*34];   // bs[j'][c] = x[c][i+du][j'-4], zero edges
  int tid = threadIdx.x;
  int t1 = tid & 15, t2 = tid >> 4;   // c1 = 2*t1, c2 = 2*t2

  float acc[2][2][9];
  #pragma unroll
  for (int p = 0; p < 2; ++p)
    #pragma unroll
    for (int q = 0; q < 2; ++q)
      #pragma unroll
      for (int v = 0; v < 9; ++v) acc[p][q][v] = 0.0f;

  if (tid < 32) {
    #pragma unroll
    for (int jj = 0; jj < 4; ++jj) { bs[jj*34 + tid] = 0.0f; bs[(132+jj)*34 + tid] = 0.0f; }
  }

  const float* xn = x + (size_t)n * 32 * 128 * 128;

  for (int i = lo; i < hi; ++i) {
    int br = i + du;
    #pragma unroll
    for (int kk = 0; kk < 4; ++kk) {
      int f = tid + 256*kk;
      int c = f >> 5;
      int j0 = (f & 31) << 2;
      float4 va = *(const float4*)(xn + (c*128 + i)*128 + j0);
      as[(j0+0)*34 + c] = va.x; as[(j0+1)*34 + c] = va.y;
      as[(j0+2)*34 + c] = va.z; as[(j0+3)*34 + c] = va.w;
      float4 vb = *(const float4*)(xn + (c*128 + br)*128 + j0);
      bs[(j0+4)*34 + c] = vb.x; bs[(j0+5)*34 + c] = vb.y;
      bs[(j0+6)*34 + c] = vb.z; bs[(j0+7)*34 + c] = vb.w;
    }
    __syncthreads();
    for (int jb = 0; jb < 16; ++jb) {
      int j0 = jb * 8;
      float2 av[8], bv[16];
      #pragma unroll
      for (int m = 0; m < 8; ++m)  av[m] = *(const float2*)&as[(j0+m)*34 + 2*t1];
      #pragma unroll
      for (int m = 0; m < 16; ++m) bv[m] = *(const float2*)&bs[(j0+m)*34 + 2*t2];
      #pragma unroll
      for (int dj = 0; dj < 8; ++dj) {
        #pragma unroll
        for (int v = 0; v < 9; ++v) {
          acc[0][0][v] += av[dj].x * bv[dj+v].x;
          acc[0][1][v] += av[dj].x * bv[dj+v].y;
          acc[1][0][v] += av[dj].y * bv[dj+v].x;
          acc[1][1][v] += av[dj].y * bv[dj+v].y;
        }
      }
    }
    __syncthreads();
  }

  int c1 = 2*t1, c2 = 2*t2;
  float* Rn = R + (size_t)n * 32 * 32 * 81;
  #pragma unroll
  for (int p = 0; p < 2; ++p)
    #pragma unroll
    for (int q = 0; q < 2; ++q)
      #pragma unroll
      for (int v = 0; v < 9; ++v)
        atomicAdd(&Rn[((c1+p)*32 + (c2+q))*81 + u*9 + v], acc[p][q][v]);
}

// ------------- P[n,(ci,u,v),co] += sum_ij x[ci,i+u-2,j+v-2]*y[co,i,j] -------
// grid = 16(n) * 5(u) * 8(chunk); block 256
__global__ __launch_bounds__(256) void k_corrP(const float* __restrict__ x,
                                               const float* __restrict__ y,
                                               float* __restrict__ P) {
  int bid = blockIdx.x;
  int n = bid / 40;
  int rem = bid % 40;
  int u = rem / 8;
  int chunk = rem % 8;
  int du = u - 2;
  int i0 = chunk * 16;
  int lo = i0, hi = i0 + 16;
  if (du < 0 && lo < -du) lo = -du;
  if (du > 0 && hi > 128 - du) hi = 128 - du;

  __shared__ float ys[64*129];   // ys[co][j], stride 129
  __shared__ float xs[132*34];   // xs[j'][ci] = x[ci][i+du][j'-2], stride 34
  int tid = threadIdx.x;
  int tco = tid & 15, tci = tid >> 4;  // co = 4*tco, ci = 2*tci
  int co = 4*tco, ci = 2*tci;

  float acc[2][4][5];
  #pragma unroll
  for (int p = 0; p < 2; ++p)
    #pragma unroll
    for (int q = 0; q < 4; ++q)
      #pragma unroll
      for (int v = 0; v < 5; ++v) acc[p][q][v] = 0.0f;

  if (tid < 32) {
    xs[0*34 + tid] = 0.0f; xs[1*34 + tid] = 0.0f;
    xs[130*34 + tid] = 0.0f; xs[131*34 + tid] = 0.0f;
  }

  const float* xn = x + (size_t)n * 32 * 128 * 128;
  const float* yn = y + (size_t)n * 64 * 128 * 128;

  for (int i = lo; i < hi; ++i) {
    int xr = i + du;
    #pragma unroll
    for (int kk = 0; kk < 8; ++kk) {   // stage y row-set: 64*128 floats
      int f = tid + 256*kk;
      int c = f >> 5;
      int j0 = (f & 31) << 2;
      float4 v = *(const float4*)(yn + (c*128 + i)*128 + j0);
      ys[c*129 + j0+0] = v.x; ys[c*129 + j0+1] = v.y;
      ys[c*129 + j0+2] = v.z; ys[c*129 + j0+3] = v.w;
    }
    #pragma unroll
    for (int kk = 0; kk < 4; ++kk) {   // stage x row-set: 32*128 floats
      int f = tid + 256*kk;
      int c = f >> 5;
      int j0 = (f & 31) << 2;
      float4 v = *(const float4*)(xn + (c*128 + xr)*128 + j0);
      xs[(j0+2)*34 + c] = v.x; xs[(j0+3)*34 + c] = v.y;
      xs[(j0+4)*34 + c] = v.z; xs[(j0+5)*34 + c] = v.w;
    }
    __syncthreads();
    for (int jb = 0; jb < 16; ++jb) {
      int j0 = jb * 8;
      float yv[4][8];
      #pragma unroll
      for (int q = 0; q < 4; ++q)
        #pragma unroll
        for (int m = 0; m < 8; ++m) yv[q][m] = ys[(co+q)*129 + j0 + m];
      float2 xv[12];
      #pragma unroll
      for (int m = 0; m < 12; ++m) xv[m] = *(const float2*)&xs[(j0+m)*34 + 2*tci];
      #pragma unroll
      for (int dj = 0; dj < 8; ++dj) {
        #pragma unroll
        for (int v = 0; v < 5; ++v) {
          #pragma unroll
          for (int q = 0; q < 4; ++q) {
            acc[0][q][v] += xv[dj+v].x * yv[q][dj];
            acc[1][q][v] += xv[dj+v].y * yv[q][dj];
          }
        }
      }
    }
    __syncthreads();
  }

  float* Pn = P + (size_t)n * 800 * 64;
  #pragma unroll
  for (int p = 0; p < 2; ++p)
    #pragma unroll
    for (int q = 0; q < 4; ++q)
      #pragma unroll
      for (int v = 0; v < 5; ++v)
        atomicAdd(&Pn[((ci+p)*25 + u*5 + v)*64 + co + q], acc[p][q][v]);
}

// -------------------- Q[n,k1,k2] = R[n,c1,c2,b-a+4,f-e+4] (+ a on diag) ----
__global__ void k_buildQ(const float* __restrict__ R, float* __restrict__ Q,
                         const float* __restrict__ alpha, const float* __restrict__ reg) {
  int bid = blockIdx.x;
  int n = bid / 800, k1 = bid % 800;
  int c1 = k1 / 25, r1 = k1 % 25, a = r1 / 5, e = r1 % 5;
  float av = alpha_scale(alpha, reg, n);
  const float* Rn = R + ((size_t)n*32 + c1) * 32 * 81;
  float* Qrow = Q + ((size_t)n*800 + k1) * 800;
  for (int k2 = threadIdx.x; k2 < 800; k2 += 256) {
    int c2 = k2 / 25, r2 = k2 % 25, b = r2 / 5, f = r2 % 5;
    float v = Rn[c2*81 + (b - a + 4)*9 + (f - e + 4)];
    if (k2 == k1) v += av;
    Qrow[k2] = v;
  }
}

// -------------------- Cholesky: diag factor + explicit inverse --------------
__global__ __launch_bounds__(256) void k_chol_diag(float* __restrict__ Q,
                                                   float* __restrict__ Linv, int t) {
  int n = blockIdx.x;
  int tid = threadIdx.x;
  __shared__ float A[80*81];
  __shared__ float B[80*81];
  float* Qn = Q + (size_t)n * 640000;
  int base = t * 80;
  for (int idx = tid; idx < 6400; idx += 256) {
    int r = idx / 80, c = idx % 80;
    A[r*81 + c] = Qn[(base + r)*800 + base + c];
  }
  __syncthreads();
  for (int j = 0; j < 80; ++j) {
    if (tid == 0) A[j*81 + j] = sqrtf(A[j*81 + j]);
    __syncthreads();
    float dinv = 1.0f / A[j*81 + j];
    for (int i = j + 1 + tid; i < 80; i += 256) A[i*81 + j] *= dinv;
    __syncthreads();
    int m = 79 - j;
    for (int idx = tid; idx < m*m; idx += 256) {
      int i = j + 1 + idx / m, k = j + 1 + idx % m;
      if (k <= i) A[i*81 + k] -= A[i*81 + j] * A[k*81 + j];
    }
    __syncthreads();
  }
  // invert lower-triangular L (column per thread)
  if (tid < 80) {
    int j = tid;
    B[j*81 + j] = 1.0f / A[j*81 + j];
    for (int i = j + 1; i < 80; ++i) {
      float s = 0.0f;
      for (int k = j; k < i; ++k) s += A[i*81 + k] * B[k*81 + j];
      B[i*81 + j] = -s / A[i*81 + i];
    }
  }
  __syncthreads();
  float* Ln = Linv + ((size_t)n*10 + t) * 6400;
  for (int idx = tid; idx < 6400; idx += 256) {
    int r = idx / 80, c = idx % 80;
    Ln[idx] = (r >= c) ? B[r*81 + c] : 0.0f;
  }
}

// panel: W = A_panel * Linv^T  (overwrites panel with L)
__global__ __launch_bounds__(256) void k_chol_panel(float* __restrict__ Q,
                                                    const float* __restrict__ Linv,
                                                    int t, int nt) {
  int n = blockIdx.x / nt, it = blockIdx.x % nt;
  int R0 = 80*(t+1) + 80*it, C0 = 80*t;
  __shared__ float As[80*82];
  __shared__ float Bs[80*82];
  float* Qn = Q + (size_t)n * 640000;
  const float* Ln = Linv + ((size_t)n*10 + t) * 6400;
  int tid = threadIdx.x;
  for (int idx = tid; idx < 6400; idx += 256) {
    int r = idx / 80, c = idx % 80;
    As[r*82 + c] = Qn[(R0 + r)*800 + C0 + c];
    Bs[r*82 + c] = Ln[idx];
  }
  __syncthreads();
  int tc = tid & 15, tr = tid >> 4;
  float acc[5][5];
  #pragma unroll
  for (int a = 0; a < 5; ++a)
    #pragma unroll
    for (int b = 0; b < 5; ++b) acc[a][b] = 0.0f;
  for (int k = 0; k < 80; ++k) {
    float av[5], bv[5];
    #pragma unroll
    for (int d = 0; d < 5; ++d) { av[d] = As[(5*tr + d)*82 + k]; bv[d] = Bs[(5*tc + d)*82 + k]; }
    #pragma unroll
    for (int a = 0; a < 5; ++a)
      #pragma unroll
      for (int b = 0; b < 5; ++b) acc[a][b] += av[a] * bv[b];
  }
  #pragma unroll
  for (int a = 0; a < 5; ++a)
    #pragma unroll
    for (int b = 0; b < 5; ++b)
      Qn[(R0 + 5*tr + a)*800 + C0 + 5*tc + b] = acc[a][b];
}

// trailing: A_IJ -= W_I * W_J^T (lower tiles only)
__global__ __launch_bounds__(256) void k_chol_trail(float* __restrict__ Q, int t, int nt) {
  int ntile = nt * (nt + 1) / 2;
  int n = blockIdx.x / ntile;
  int rr = blockIdx.x % ntile;
  int i = 0;
  while (rr >= i + 1) { rr -= (i + 1); ++i; }
  int j = rr;
  int R0 = 80*(t+1+i), C0 = 80*(t+1+j), K0 = 80*t;
  __shared__ float Ws[80*82];
  __shared__ float Vs[80*82];
  float* Qn = Q + (size_t)n * 640000;
  int tid = threadIdx.x;
  for (int idx = tid; idx < 6400; idx += 256) {
    int r = idx / 80, c = idx % 80;
    Ws[r*82 + c] = Qn[(R0 + r)*800 + K0 + c];
    Vs[r*82 + c] = Qn[(C0 + r)*800 + K0 + c];
  }
  __syncthreads();
  int tc = tid & 15, tr = tid >> 4;
  float acc[5][5];
  #pragma unroll
  for (int a = 0; a < 5; ++a)
    #pragma unroll
    for (int b = 0; b < 5; ++b) acc[a][b] = 0.0f;
  for (int k = 0; k < 80; ++k) {
    float av[5], bv[5];
    #pragma unroll
    for (int d = 0; d < 5; ++d) { av[d] = Ws[(5*tr + d)*82 + k]; bv[d] = Vs[(5*tc + d)*82 + k]; }
    #pragma unroll
    for (int a = 0; a < 5; ++a)
      #pragma unroll
      for (int b = 0; b < 5; ++b) acc[a][b] += av[a] * bv[b];
  }
  #pragma unroll
  for (int a = 0; a < 5; ++a)
    #pragma unroll
    for (int b = 0; b < 5; ++b)
      Qn[(R0 + 5*tr + a)*800 + C0 + 5*tc + b] -= acc[a][b];
}

// -------------------- blocked triangular solves + output transpose ---------
// grid = 16(n) * 8(col groups of 8); block 256
__global__ __launch_bounds__(256) void k_solve(const float* __restrict__ Q,
                                               const float* __restrict__ Linv,
                                               const float* __restrict__ P,
                                               float* __restrict__ out) {
  int n = blockIdx.x >> 3;
  int g = blockIdx.x & 7;
  int tid = threadIdx.x;
  __shared__ float z[800*8];
  __shared__ float Lt[80*82];
  const float* Qn = Q + (size_t)n * 640000;

  for (int idx = tid; idx < 6400; idx += 256) {
    int k = idx >> 3, c = idx & 7;
    z[idx] = P[(n*800 + k)*64 + g*8 + c];
  }
  __syncthreads();

  // forward: L z = P
  for (int t = 0; t < 10; ++t) {
    for (int s = 0; s < t; ++s) {
      for (int idx = tid; idx < 6400; idx += 256)
        Lt[(idx/80)*82 + (idx%80)] = Qn[(80*t + idx/80)*800 + 80*s + idx%80];
      __syncthreads();
      for (int e = 0; e < 3; ++e) {
        int idx = tid + 256*e;
        if (idx < 640) {
          int c = idx & 7, r = idx >> 3;
          float acc = 0.0f;
          #pragma unroll 4
          for (int k = 0; k < 80; ++k) acc += Lt[r*82 + k] * z[(80*s + k)*8 + c];
          z[(80*t + r)*8 + c] -= acc;
        }
      }
      __syncthreads();
    }
    {
      const float* Ln = Linv + ((size_t)n*10 + t) * 6400;
      for (int idx = tid; idx < 6400; idx += 256)
        Lt[(idx/80)*82 + (idx%80)] = Ln[idx];
      __syncthreads();
      float tv[3];
      for (int e = 0; e < 3; ++e) {
        int idx = tid + 256*e;
        if (idx < 640) {
          int c = idx & 7, r = idx >> 3;
          float acc = 0.0f;
          #pragma unroll 4
          for (int k = 0; k < 80; ++k) acc += Lt[r*82 + k] * z[(80*t + k)*8 + c];
          tv[e] = acc;
        }
      }
      __syncthreads();
      for (int e = 0; e < 3; ++e) {
        int idx = tid + 256*e;
        if (idx < 640) { int c = idx & 7, r = idx >> 3; z[(80*t + r)*8 + c] = tv[e]; }
      }
      __syncthreads();
    }
  }

  // backward: L^T D = z
  for (int t = 9; t >= 0; --t) {
    for (int s = t + 1; s < 10; ++s) {
      for (int idx = tid; idx < 6400; idx += 256)
        Lt[(idx/80)*82 + (idx%80)] = Qn[(80*s + idx/80)*800 + 80*t + idx%80];
      __syncthreads();
      for (int e = 0; e < 3; ++e) {
        int idx = tid + 256*e;
        if (idx < 640) {
          int c = idx & 7, r = idx >> 3;
          float acc = 0.0f;
          #pragma unroll 4
          for (int k = 0; k < 80; ++k) acc += Lt[k*82 + r] * z[(80*s + k)*8 + c];
          z[(80*t + r)*8 + c] -= acc;
        }
      }
      __syncthreads();
    }
    {
      const float* Ln = Linv + ((size_t)n*10 + t) * 6400;
      for (int idx = tid; idx < 6400; idx += 256)
        Lt[(idx/80)*82 + (idx%80)] = Ln[idx];
      __syncthreads();
      float tv[3];
      for (int e = 0; e < 3; ++e) {
        int idx = tid + 256*e;
        if (idx < 640) {
          int c = idx & 7, r = idx >> 3;
          float acc = 0.0f;
          #pragma unroll 4
          for (int k = 0; k < 80; ++k) acc += Lt[k*82 + r] * z[(80*t + k)*8 + c];
          tv[e] = acc;
        }
      }
      __syncthreads();
      for (int e = 0; e < 3; ++e) {
        int idx = tid + 256*e;
        if (idx < 640) { int c = idx & 7, r = idx >> 3; z[(80*t + r)*8 + c] = tv[e]; }
      }
      __syncthreads();
    }
  }

  // out[n][co][k] = z[k][c]
  for (int idx = tid; idx < 6400; idx += 256) {
    int c = idx / 800, k = idx % 800;
    out[(size_t)(n*64 + g*8 + c)*800 + k] = z[k*8 + c];
  }
}

extern "C" void kernel_launch(void* const* d_in, const int* in_sizes, int n_in,
                              void* d_out, int out_size, void* d_ws, size_t ws_size,
                              hipStream_t stream) {
  const float* x     = (const float*)d_in[0];
  const float* d     = (const float*)d_in[1];
  const float* y     = (const float*)d_in[2];
  const float* alpha = (const float*)d_in[3];
  const float* reg   = (const float*)d_in[4];
  float* out = (float*)d_out;
  float* ws  = (float*)d_ws;

  float* R  = ws;
  float* Q  = ws + R_SZ;
  float* P  = ws + R_SZ + Q_SZ;
  float* Li = ws + R_SZ + Q_SZ + P_SZ;

  k_init<<<(R_SZ + P_SZ) / 256, 256, 0, stream>>>(R, P, d, alpha, reg);
  k_corrR<<<16*9*8, 256, 0, stream>>>(x, R);
  k_buildQ<<<16*800, 256, 0, stream>>>(R, Q, alpha, reg);
  k_corrP<<<16*5*8, 256, 0, stream>>>(x, y, P);

  for (int t = 0; t < 10; ++t) {
    k_chol_diag<<<16, 256, 0, stream>>>(Q, Li, t);
    int nt = 9 - t;
    if (nt > 0) {
      k_chol_panel<<<16*nt, 256, 0, stream>>>(Q, Li, t, nt);
      k_chol_trail<<<16*nt*(nt+1)/2, 256, 0, stream>>>(Q, t, nt);
    }
  }

  k_solve<<<128, 256, 0, stream>>>(Q, Li, P, out);
}